// Round 6
// baseline (278.899 us; speedup 1.0000x reference)
//
#include <hip/hip_runtime.h>
#include <hip/hip_bf16.h>

// B=4, L=2048, D=1024, H=16, HD=64. fp32 in/out.
// convw/convk (flat fp32->bf16) ; convv (transpose to [b,h,d,key]) ;
// attn (flash S^T form, FRAGMENT-ORDER LDS staging via gld16 -> conflict-free
// ds_read at base+lane*16, in-register P transform) ;
// proj GEMM (fragment-order staging, BK=64, async dbuf).
// Kb/Vb scratch lives in d_out (dead before proj writes Y).

#define B_  4
#define L_  2048
#define D_  1024
#define H_  16

typedef float  f32x4  __attribute__((ext_vector_type(4)));
typedef short  bf16x8 __attribute__((ext_vector_type(8)));
typedef short  bf16x4 __attribute__((ext_vector_type(4)));

__device__ inline unsigned short f2bf(float x) {          // RNE
    union { float f; unsigned u; } v; v.f = x;
    unsigned r = v.u + 0x7FFFu + ((v.u >> 16) & 1u);
    return (unsigned short)(r >> 16);
}
__device__ inline unsigned pack_trunc2(float lo, float hi) {
    union { float f; unsigned u; } a, b; a.f = lo; b.f = hi;
    return (a.u >> 16) | (b.u & 0xFFFF0000u);
}
__device__ inline float fast_exp2(float x) {
#if __has_builtin(__builtin_amdgcn_exp2f)
    return __builtin_amdgcn_exp2f(x);
#else
    return exp2f(x);
#endif
}
__device__ inline bf16x8 pack8s(float4 a, float4 b, float s) {
    bf16x8 r;
    r[0] = (short)f2bf(a.x * s); r[1] = (short)f2bf(a.y * s);
    r[2] = (short)f2bf(a.z * s); r[3] = (short)f2bf(a.w * s);
    r[4] = (short)f2bf(b.x * s); r[5] = (short)f2bf(b.y * s);
    r[6] = (short)f2bf(b.z * s); r[7] = (short)f2bf(b.w * s);
    return r;
}
__device__ inline void gld16(const void* g, void* l) {    // async global->LDS, 16B/lane
    __builtin_amdgcn_global_load_lds(
        (const __attribute__((address_space(1))) void*)g,
        (__attribute__((address_space(3))) void*)l, 16, 0, 0);
}

// ---------------- W fp32 -> bf16 (flat) ----------------
__global__ __launch_bounds__(256) void convw_kernel(const float* __restrict__ W,
                                                    unsigned short* __restrict__ Wb) {
    int i = (blockIdx.x * 256 + threadIdx.x) * 4;
    float4 v = *(const float4*)&W[i];
    bf16x4 o;
    o[0] = (short)f2bf(v.x); o[1] = (short)f2bf(v.y);
    o[2] = (short)f2bf(v.z); o[3] = (short)f2bf(v.w);
    *(bf16x4*)&Wb[i] = o;
}

// ---------------- V fp32 -> bf16 transposed [b,h,d,key] (plain, no swizzle) ----------------
__global__ __launch_bounds__(256) void convv_kernel(const float* __restrict__ V,
                                                    unsigned short* __restrict__ Vb) {
    __shared__ __align__(16) unsigned short T[64 * 72];  // [d][key], pad 72
    int tid = threadIdx.x;
    int kb_ = blockIdx.x & 31, bh = blockIdx.x >> 5;
    int b = bh >> 4, h = bh & 15, k0 = kb_ * 64;
    int kl = tid >> 4;
    int d4 = (tid & 15) * 4;
    #pragma unroll
    for (int pp = 0; pp < 4; ++pp) {
        int key = pp * 16 + kl;
        const float* p = V + ((size_t)(b * L_ + k0 + key)) * D_ + h * 64 + d4;
        float4 v = *(const float4*)p;    // coalesced: 16 lanes cover one 256B row
        T[(d4 + 0) * 72 + key] = f2bf(v.x);
        T[(d4 + 1) * 72 + key] = f2bf(v.y);
        T[(d4 + 2) * 72 + key] = f2bf(v.z);
        T[(d4 + 3) * 72 + key] = f2bf(v.w);
    }
    __syncthreads();
    #pragma unroll
    for (int i = 0; i < 2; ++i) {
        int c = i * 256 + tid; int d = c >> 3, ch = c & 7;
        bf16x8 v = *(const bf16x8*)&T[d * 72 + ch * 8];
        *(bf16x8*)&Vb[((size_t)(b * H_ + h) * 64 + d) * L_ + k0 + ch * 8] = v;
    }
}

// ---------------- flash attention (S^T form), 128 q/block, frag-order LDS ----------------
// Ks chunk layout: [nt 4][ksHalf 2][lane 64] ; lane(quad,l16) holds K[key=nt*16+l16][d-octet ksHalf*4+quad]
// Vt chunk layout: [dt 4][ksHalf 2][lane 64] ; lane holds V^T[d=dt*16+l16][key-octet ksHalf*4+quad]
__global__ __launch_bounds__(256, 4) void attn_kernel(const float* __restrict__ Qg,
                                                      const unsigned short* __restrict__ Kb,
                                                      const unsigned short* __restrict__ Vb,
                                                      unsigned short* __restrict__ Og) {
    __shared__ unsigned short Ks[2][64 * 64];
    __shared__ unsigned short Vt[2][64 * 64];

    const int tid  = threadIdx.x;
    const int w    = tid >> 6;
    const int lane = tid & 63;
    const int l16  = lane & 15;
    const int quad = lane >> 4;

    // XCD swizzle: 16 q-blocks of one (b,h) on one XCD
    const int x   = blockIdx.x;
    const int idx = x >> 3;
    const int bh  = (x & 7) * 8 + (idx & 7);
    const int qb  = idx >> 3;
    const int bz  = bh >> 4;
    const int h   = bh & 15;
    const int q0  = qb * 128;

    const float qscale = 0.04508422f;           // log2(e)/32
    bf16x8 aq[2][2];
    #pragma unroll
    for (int qt = 0; qt < 2; ++qt) {
        const int qrow = q0 + w * 32 + qt * 16 + l16;
        const float* qp = Qg + ((size_t)(bz * L_ + qrow)) * D_ + h * 64 + quad * 8;
        aq[qt][0] = pack8s(*(const float4*)qp,        *(const float4*)(qp + 4),  qscale);
        aq[qt][1] = pack8s(*(const float4*)(qp + 32), *(const float4*)(qp + 36), qscale);
    }

    f32x4 o[2][4];
    float lsum[2] = {0.f, 0.f};
    #pragma unroll
    for (int qt = 0; qt < 2; ++qt)
        #pragma unroll
        for (int i = 0; i < 4; ++i) o[qt][i] = (f32x4){0.f, 0.f, 0.f, 0.f};

    const unsigned short* Kbh = Kb + ((size_t)bz * L_ * H_ + h) * 64;  // + key*1024 + d
    const unsigned short* Vbh = Vb + (size_t)(bz * H_ + h) * 64 * L_;  // + d*L_ + key
    const int hi = quad >> 1;                   // destination-side selector for P transform
    const int i0 = (quad & 1) * 32 + l16;       // shfl source lanes
    const int i1 = i0 + 16;

    // fragment-order staging: chunk c -> LDS offset c*16B (lane-contiguous per wave-instr)
    #define ISSUE(T, BUF)                                                           \
        {                                                                           \
            int k0_ = (T) * 64;                                                     \
            _Pragma("unroll")                                                       \
            for (int i = 0; i < 2; ++i) {                                           \
                int c   = i * 256 + tid;                                            \
                int tt  = (c >> 7) & 3;          /* nt (K) or dt (V) */             \
                int jj  = ((c >> 6) & 1) * 4 + ((c >> 4) & 3);  /* octet */         \
                int e16 = c & 15;                                                   \
                gld16(Kbh + (size_t)(k0_ + tt * 16 + e16) * (H_ * 64) + jj * 8,     \
                      (char*)Ks[BUF] + (i * 256 + w * 64) * 16);                    \
                gld16(Vbh + (size_t)(tt * 16 + e16) * L_ + k0_ + jj * 8,            \
                      (char*)Vt[BUF] + (i * 256 + w * 64) * 16);                    \
            }                                                                       \
        }

    ISSUE(0, 0)

    for (int t = 0; t < 32; ++t) {
        __syncthreads();                        // drains this tile's DMA
        if (t < 31) ISSUE(t + 1, (t + 1) & 1)   // next tile in flight across compute
        const unsigned short* ks = Ks[t & 1];
        const unsigned short* vt = Vt[t & 1];

        // ---- S^T = K Q^T : lane holds S^T[key = nt*16+quad*4+r][q = qt*16+l16] ----
        f32x4 s[2][4];
        #pragma unroll
        for (int nt = 0; nt < 4; ++nt) {
            bf16x8 k0f = *(const bf16x8*)&ks[(nt * 128 + lane) * 8];        // conflict-free
            bf16x8 k1f = *(const bf16x8*)&ks[(nt * 128 + 64 + lane) * 8];
            #pragma unroll
            for (int qt = 0; qt < 2; ++qt) {
                f32x4 z = (f32x4){0.f, 0.f, 0.f, 0.f};
                z = __builtin_amdgcn_mfma_f32_16x16x32_bf16(k0f, aq[qt][0], z, 0, 0, 0);
                s[qt][nt] = __builtin_amdgcn_mfma_f32_16x16x32_bf16(k1f, aq[qt][1], z, 0, 0, 0);
            }
        }

        // ---- P = exp2(S^T), packed (even,odd key) pairs ----
        unsigned packed[2][4][2];
        #pragma unroll
        for (int qt = 0; qt < 2; ++qt)
            #pragma unroll
            for (int nt = 0; nt < 4; ++nt) {
                float p0 = fast_exp2(s[qt][nt][0]), p1 = fast_exp2(s[qt][nt][1]);
                float p2 = fast_exp2(s[qt][nt][2]), p3 = fast_exp2(s[qt][nt][3]);
                lsum[qt] += (p0 + p1) + (p2 + p3);
                packed[qt][nt][0] = pack_trunc2(p0, p1);
                packed[qt][nt][1] = pack_trunc2(p2, p3);
            }

        // ---- in-register C->A transform: shuffle both nt variants, select by DEST hi ----
        bf16x8 pav[2][2];
        #pragma unroll
        for (int qt = 0; qt < 2; ++qt) {
            union { int i[4]; bf16x8 v; } u0, u1;
            #pragma unroll
            for (int fp = 0; fp < 4; ++fp) {
                int src = (fp & 2) ? i1 : i0;
                int f   = fp & 1;
                int lo0 = __shfl((int)packed[qt][0][f], src);
                int hi0 = __shfl((int)packed[qt][1][f], src);
                u0.i[fp] = hi ? hi0 : lo0;
                int lo1 = __shfl((int)packed[qt][2][f], src);
                int hi1 = __shfl((int)packed[qt][3][f], src);
                u1.i[fp] = hi ? hi1 : lo1;
            }
            pav[qt][0] = u0.v; pav[qt][1] = u1.v;
        }

        // ---- O += P V ----
        #pragma unroll
        for (int dt = 0; dt < 4; ++dt) {
            bf16x8 v0 = *(const bf16x8*)&vt[(dt * 128 + lane) * 8];         // conflict-free
            bf16x8 v1 = *(const bf16x8*)&vt[(dt * 128 + 64 + lane) * 8];
            #pragma unroll
            for (int qt = 0; qt < 2; ++qt) {
                o[qt][dt] = __builtin_amdgcn_mfma_f32_16x16x32_bf16(pav[qt][0], v0, o[qt][dt], 0, 0, 0);
                o[qt][dt] = __builtin_amdgcn_mfma_f32_16x16x32_bf16(pav[qt][1], v1, o[qt][dt], 0, 0, 0);
            }
        }
    }

    // ---- deferred row-sum reduction ----
    float tot[2];
    #pragma unroll
    for (int qt = 0; qt < 2; ++qt) {
        float v = lsum[qt];
        v += __shfl_xor(v, 16); v += __shfl_xor(v, 32);
        tot[qt] = v;                            // full sum for q = qt*16 + l16
    }
    #pragma unroll
    for (int qt = 0; qt < 2; ++qt)
        #pragma unroll
        for (int r = 0; r < 4; ++r) {
            float tv  = __shfl(tot[qt], quad * 4 + r);
            float inv = 1.0f / tv;
            int q = q0 + w * 32 + qt * 16 + quad * 4 + r;
            size_t rowb = ((size_t)(bz * L_ + q)) * D_ + h * 64;
            #pragma unroll
            for (int dt = 0; dt < 4; ++dt)
                Og[rowb + dt * 16 + l16] = f2bf(o[qt][dt][r] * inv);
        }
}

// ---------------- projection: Y = O @ W^T + b, frag-order staging, BK=64 ----------------
// As chunks: [wm 2][mt 4][ksq 2][lane 64] ; lane(quad,l16) holds O[row=wm*64+mt*16+l16][octet ksq*4+quad]
__global__ __launch_bounds__(256, 2) void proj_kernel(const unsigned short* __restrict__ Og,
                                                      const unsigned short* __restrict__ Wb,
                                                      const float* __restrict__ bias,
                                                      float* __restrict__ Yg) {
    __shared__ unsigned short As[2][128 * 64];
    __shared__ unsigned short Bs[2][128 * 64];

    const int tid  = threadIdx.x;
    const int w    = tid >> 6;
    const int lane = tid & 63;
    const int l16  = lane & 15;
    const int quad = lane >> 4;
    const int wm   = w & 1, wn = w >> 1;

    const int m0 = blockIdx.x * 128;
    const int n0 = blockIdx.y * 128;

    f32x4 acc[4][4];
    #pragma unroll
    for (int i = 0; i < 4; ++i)
        #pragma unroll
        for (int j = 0; j < 4; ++j) acc[i][j] = (f32x4){0.f, 0.f, 0.f, 0.f};

    #define PISSUE(T, BUF)                                                          \
        {                                                                           \
            int kt_ = (T) * 64;                                                     \
            _Pragma("unroll")                                                       \
            for (int i = 0; i < 4; ++i) {                                           \
                int c   = i * 256 + tid;                                            \
                int hm  = c >> 9;                 /* wm / wn region */              \
                int mt  = (c >> 7) & 3;                                             \
                int jj  = ((c >> 6) & 1) * 4 + ((c >> 4) & 3);                      \
                int row = hm * 64 + mt * 16 + (c & 15);                             \
                gld16(&Og[(size_t)(m0 + row) * 1024 + kt_ + jj * 8],                \
                      (char*)As[BUF] + (i * 256 + w * 64) * 16);                    \
                gld16(&Wb[(size_t)(n0 + row) * 1024 + kt_ + jj * 8],                \
                      (char*)Bs[BUF] + (i * 256 + w * 64) * 16);                    \
            }                                                                       \
        }

    PISSUE(0, 0)

    for (int t = 0; t < 16; ++t) {
        __syncthreads();
        if (t < 15) PISSUE(t + 1, (t + 1) & 1)
        const unsigned short* as = As[t & 1];
        const unsigned short* bs = Bs[t & 1];

        #pragma unroll
        for (int ksq = 0; ksq < 2; ++ksq) {
            bf16x8 a[4], b[4];
            #pragma unroll
            for (int mt = 0; mt < 4; ++mt)
                a[mt] = *(const bf16x8*)&as[(((wm * 4 + mt) * 2 + ksq) * 64 + lane) * 8];
            #pragma unroll
            for (int nt = 0; nt < 4; ++nt)
                b[nt] = *(const bf16x8*)&bs[(((wn * 4 + nt) * 2 + ksq) * 64 + lane) * 8];
            #pragma unroll
            for (int mt = 0; mt < 4; ++mt)
                #pragma unroll
                for (int nt = 0; nt < 4; ++nt)
                    acc[mt][nt] = __builtin_amdgcn_mfma_f32_16x16x32_bf16(a[mt], b[nt], acc[mt][nt], 0, 0, 0);
        }
    }

    #pragma unroll
    for (int mt = 0; mt < 4; ++mt)
        #pragma unroll
        for (int nt = 0; nt < 4; ++nt) {
            int e = n0 + wn * 64 + nt * 16 + l16;
            float bv = bias[e];
            #pragma unroll
            for (int r = 0; r < 4; ++r) {
                int m = m0 + wm * 64 + mt * 16 + quad * 4 + r;
                Yg[(size_t)m * 1024 + e] = acc[mt][nt][r] + bv;
            }
        }
}

extern "C" void kernel_launch(void* const* d_in, const int* in_sizes, int n_in,
                              void* d_out, int out_size, void* d_ws, size_t ws_size,
                              hipStream_t stream) {
    const float* Q    = (const float*)d_in[0];
    const float* K    = (const float*)d_in[1];
    const float* V    = (const float*)d_in[2];
    const float* W    = (const float*)d_in[3];
    const float* bias = (const float*)d_in[4];
    float* Y = (float*)d_out;

    unsigned short* Og = (unsigned short*)d_ws;                                     // 16 MiB
    unsigned short* Wb = (unsigned short*)((char*)d_ws + (size_t)16 * 1024 * 1024); // 2 MiB
    // Kb/Vb scratch in d_out (33.5 MiB) — dead before proj overwrites with Y
    unsigned short* Kb = (unsigned short*)d_out;
    unsigned short* Vb = Kb + (size_t)B_ * H_ * L_ * 64;

    convw_kernel<<<D_ * D_ / (256 * 4), 256, 0, stream>>>(W, Wb);
    // K: flat convert (Kb layout [b,key,h*64+d] == flat K)
    convw_kernel<<<B_ * L_ * D_ / (256 * 4), 256, 0, stream>>>(K, Kb);
    convv_kernel<<<B_ * H_ * (L_ / 64), 256, 0, stream>>>(V, Vb);
    attn_kernel<<<B_ * H_ * (L_ / 128), 256, 0, stream>>>(Q, Kb, Vb, Og);
    dim3 pg(B_ * L_ / 128, D_ / 128);
    proj_kernel<<<pg, 256, 0, stream>>>(Og, Wb, bias, Y);
}